// Round 10
// baseline (191.165 us; speedup 1.0000x reference)
//
#include <hip/hip_runtime.h>

typedef unsigned short u16;
typedef unsigned int u32;
typedef unsigned long long u64;
typedef __bf16 bf16x8 __attribute__((ext_vector_type(8)));
typedef float f32x4 __attribute__((ext_vector_type(4)));
typedef unsigned short ushort8 __attribute__((ext_vector_type(8)));
typedef int v4i __attribute__((ext_vector_type(4)));
typedef int v8i __attribute__((ext_vector_type(8)));

#define NEGF (-1e30f)
#define HAD_SCALE 0.08838834764831845f   // 128^-0.5
#define WCONST 0.011048543456039806f     // 128^-0.5 * 64^-0.5
#define SA 64.0f                          // q_lora fp8 scale
#define SB 1024.0f                        // wq_b fp8 scale
#define DEQ (1.0f / 65536.0f)             // 1/(SA*SB)
#define SCL1 0x7f7f7f7f                   // e8m0 scale = 1.0 in every byte

__device__ __forceinline__ float b2f(u16 u) {
  union { u32 i; float f; } x; x.i = ((u32)u) << 16; return x.f;
}
__device__ __forceinline__ u16 f2b(float f) {  // RNE f32->bf16
  u32 u = __float_as_uint(f);
  return (u16)((u + 0x7fffu + ((u >> 16) & 1u)) >> 16);
}
__device__ __forceinline__ float bfr(float f) { return b2f(f2b(f)); }

__device__ __forceinline__ void async_cp16(void* lds, const void* g) {
  __builtin_amdgcn_global_load_lds((__attribute__((address_space(1))) void*)g,
                                   (__attribute__((address_space(3))) void*)lds, 16, 0, 0);
}

__device__ __forceinline__ u32 pk4_fp8(float a, float b, float c, float d) {
  u32 w = (u32)__builtin_amdgcn_cvt_pk_fp8_f32(a, b, 0, false);
  w = (u32)__builtin_amdgcn_cvt_pk_fp8_f32(c, d, (int)w, true);
  return w;
}

__device__ __forceinline__ v8i cat8(v4i lo, v4i hi) {
  return __builtin_shufflevector(lo, hi, 0, 1, 2, 3, 4, 5, 6, 7);
}

// Packed-fragment layout (16-row blocks) — unchanged from round 8.
__device__ __forceinline__ size_t pk_granule(int r4, int k) {
  return (size_t)((k >> 6) * 1024 + (((k >> 3) & 3) * 16 + r4) * 16 + (((k >> 5) & 1) * 8));
}
__device__ __forceinline__ int pk_u32_idx(int r4, int li) {
  return (li >> 4) * 256 + (((li >> 1) & 3) * 16 + r4) * 4 + ((li >> 3) & 1) * 2 + (li & 1);
}

// ---------------- bf16 tile transpose (wk / wproj -> BT2) --------------------
__device__ __forceinline__ void tr_tile(const void* src, u16* dst, int Nn,
                                        int dpitch, int f32src, int k0, int n0,
                                        u16* tl) {
  int tid = threadIdx.x;
  int kk = tid >> 3, nc = tid & 7;
  u16 v[8];
  if (f32src) {
    const float* s = (const float*)src + (size_t)(k0 + kk) * Nn + n0 + nc * 8;
#pragma unroll
    for (int j = 0; j < 8; ++j) v[j] = f2b(s[j]);
  } else {
    const u16* s = (const u16*)src + (size_t)(k0 + kk) * Nn + n0 + nc * 8;
    ushort8 x = *(const ushort8*)s;
#pragma unroll
    for (int j = 0; j < 8; ++j) v[j] = x[j];
  }
#pragma unroll
  for (int j = 0; j < 8; ++j) tl[(nc * 8 + j) * 56 + kk] = v[j];
  __syncthreads();
  int n = tid >> 2, kc = tid & 3;
  ushort8 o = *(const ushort8*)(tl + n * 56 + kc * 8);
  *(ushort8*)(dst + (size_t)(n0 + n) * dpitch + k0 + kc * 8) = o;
}

// ------- prep: wq_b -> wq8 (fp8 packed), q_lora -> aq8 (fp8 packed), BT2 -----
__global__ __launch_bounds__(256) void prep_transpose(const u16* __restrict__ wq_b,
                                                      const u16* __restrict__ wk,
                                                      const float* __restrict__ wproj,
                                                      const u16* __restrict__ q_lora,
                                                      unsigned char* __restrict__ wq8,
                                                      unsigned char* __restrict__ aq8,
                                                      u16* __restrict__ BT2) {
  __shared__ u16 tl[64 * 72];
  int b = blockIdx.x, tid = threadIdx.x;
  if (b < 3072) {        // wq_b (1536,8192) -> wq8 packed, tile 64k x 64n
    int kt0 = (b % 24) * 64, n0 = (b / 24) * 64;
#pragma unroll
    for (int i = 0; i < 2; ++i) {
      int s = i * 256 + tid;
      int row = s >> 3, c = s & 7;
      ushort8 x = *(const ushort8*)(wq_b + (size_t)(kt0 + row) * 8192 + n0 + c * 8);
#pragma unroll
      for (int j = 0; j < 8; ++j) tl[(c * 8 + j) * 72 + row] = x[j];
    }
    __syncthreads();
    int n = tid >> 2, kc = tid & 3;
    const u16* src = tl + n * 72 + kc * 16;
    u32 w[4];
#pragma unroll
    for (int g = 0; g < 4; ++g)
      w[g] = pk4_fp8(b2f(src[4 * g]) * SB, b2f(src[4 * g + 1]) * SB,
                     b2f(src[4 * g + 2]) * SB, b2f(src[4 * g + 3]) * SB);
    int gn = n0 + n;
    int k1 = kt0 + kc * 16;
    size_t ga = (size_t)(gn >> 4) * 24576 + pk_granule(gn & 15, k1);
    *(u64*)(wq8 + ga) = (u64)w[0] | ((u64)w[1] << 32);
    *(u64*)(wq8 + ga + 256) = (u64)w[2] | ((u64)w[3] << 32);
  } else if (b < 3520) { // wk (7168,128) -> BT2 rows 0..127
    int g = b - 3072;
    tr_tile(wk, BT2, 128, 7168, 0, (g % 224) * 32, (g / 224) * 64, tl);
  } else if (b < 3744) { // wproj (7168,64) f32 -> BT2 rows 128..191
    int g = b - 3520;
    tr_tile(wproj, BT2 + (size_t)128 * 7168, 64, 7168, 1, g * 32, 0, tl);
  } else if (b < 3808) { // zero BT2 rows 192..255
    int r = 192 + (b - 3744);
    ushort8 z = {0, 0, 0, 0, 0, 0, 0, 0};
    u16* row = BT2 + (size_t)r * 7168;
    for (int i = tid; i < 896; i += 256) *(ushort8*)(row + i * 8) = z;
  } else {               // q_lora (1024,1536) -> aq8 packed
    int mb = b - 3808;
#pragma unroll
    for (int it = 0; it < 6; ++it) {
      int id = it * 256 + tid;
      int c = id >> 4, r = id & 15;
      const u16* src = q_lora + (size_t)(mb * 16 + r) * 1536 + c * 16;
      ushort8 x0 = *(const ushort8*)src;
      ushort8 x1 = *(const ushort8*)(src + 8);
      u32 w0 = pk4_fp8(b2f(x0[0]) * SA, b2f(x0[1]) * SA, b2f(x0[2]) * SA, b2f(x0[3]) * SA);
      u32 w1 = pk4_fp8(b2f(x0[4]) * SA, b2f(x0[5]) * SA, b2f(x0[6]) * SA, b2f(x0[7]) * SA);
      u32 w2 = pk4_fp8(b2f(x1[0]) * SA, b2f(x1[1]) * SA, b2f(x1[2]) * SA, b2f(x1[3]) * SA);
      u32 w3 = pk4_fp8(b2f(x1[4]) * SA, b2f(x1[5]) * SA, b2f(x1[6]) * SA, b2f(x1[7]) * SA);
      size_t ga = (size_t)mb * 24576 + pk_granule(r, c * 16);
      *(u64*)(aq8 + ga) = (u64)w0 | ((u64)w1 << 32);
      *(u64*)(aq8 + ga + 256) = (u64)w2 | ((u64)w3 << 32);
    }
  }
}

// ------- planar-4 row op: RoPE -> FWHT-128 -> fp8 quant ----------------------
__device__ __forceinline__ void planar4(float v0, float v1, float v2, float v3,
                                        int li, float4 c4, float4 s4,
                                        u32* __restrict__ dst_word,
                                        float* __restrict__ dstscale) {
  float p0 = __shfl_xor(v0, 8, 64);
  float p1 = __shfl_xor(v1, 8, 64);
  float p2 = __shfl_xor(v2, 8, 64);
  float p3 = __shfl_xor(v3, 8, 64);
  if (li < 8) {
    v0 = bfr(v0 * c4.x - p0 * s4.x); v1 = bfr(v1 * c4.y - p1 * s4.y);
    v2 = bfr(v2 * c4.z - p2 * s4.z); v3 = bfr(v3 * c4.w - p3 * s4.w);
  } else if (li < 16) {
    v0 = bfr(v0 * c4.x + p0 * s4.x); v1 = bfr(v1 * c4.y + p1 * s4.y);
    v2 = bfr(v2 * c4.z + p2 * s4.z); v3 = bfr(v3 * c4.w + p3 * s4.w);
  }
  { float a = v0 + v1, b = v0 - v1; v0 = a; v1 = b; }
  { float a = v2 + v3, b = v2 - v3; v2 = a; v3 = b; }
  { float a = v0 + v2, b = v0 - v2; v0 = a; v2 = b; }
  { float a = v1 + v3, b = v1 - v3; v1 = a; v3 = b; }
#pragma unroll
  for (int m = 1; m <= 16; m <<= 1) {
    float q0 = __shfl_xor(v0, m, 64), q1 = __shfl_xor(v1, m, 64);
    float q2 = __shfl_xor(v2, m, 64), q3 = __shfl_xor(v3, m, 64);
    if (li & m) { v0 = q0 - v0; v1 = q1 - v1; v2 = q2 - v2; v3 = q3 - v3; }
    else        { v0 += q0;     v1 += q1;     v2 += q2;     v3 += q3; }
  }
  v0 = bfr(v0 * HAD_SCALE); v1 = bfr(v1 * HAD_SCALE);
  v2 = bfr(v2 * HAD_SCALE); v3 = bfr(v3 * HAD_SCALE);
  float am = fmaxf(fmaxf(fabsf(v0), fabsf(v1)), fmaxf(fabsf(v2), fabsf(v3)));
#pragma unroll
  for (int m = 1; m <= 16; m <<= 1) am = fmaxf(am, __shfl_xor(am, m, 64));
  am = fmaxf(am, 1e-4f);
  float scale = am / 448.0f;
  float inv = 1.0f / scale;
  *dst_word = pk4_fp8(v0 * inv, v1 * inv, v2 * inv, v3 * inv);
  if (li == 0) *dstscale = scale;
}

// ======== merged: [blk<256] k/w GEMM split-K=8 (bf16, long blocks FIRST) =====
// ======== [blk>=256] q GEMM (MX fp8 K=128, no-LDS K-loop) + fused epilogue ===
__global__ __launch_bounds__(256) void gemm_merged(const unsigned char* __restrict__ A,
                                                   const unsigned char* __restrict__ B,
                                                   const float* __restrict__ cs,
                                                   const int* __restrict__ positions,
                                                   u32* __restrict__ q_fp8,
                                                   float* __restrict__ q_scale,
                                                   const u16* __restrict__ hidden,
                                                   const u16* __restrict__ BT2,
                                                   float* __restrict__ part) {
  __shared__ unsigned char smem[17408];
  int tid = threadIdx.x, wid = tid >> 6, lane = tid & 63, lo = lane & 15, quad = lane >> 4;

  if (blockIdx.x < 256) {
    // ---------------- k/w GEMM: 64x128 tile, BK=64, split-K=8 ----------------
    u16* As = (u16*)smem;
    u16* Bs = (u16*)smem + 4096;
    int flat = blockIdx.x;               // z == xcd (flat&7)
    int z = flat & 7, up = flat >> 3;
    int m0 = (up & 15) * 64, n0 = (up >> 4) * 128;
    int mrow = (wid & 1) * 32, nrow = (wid >> 1) * 64;
    f32x4 zero4 = {0.f, 0.f, 0.f, 0.f};
    f32x4 acc[2][4];
#pragma unroll
    for (int a = 0; a < 2; ++a)
#pragma unroll
      for (int b = 0; b < 4; ++b) acc[a][b] = zero4;
    for (int kb = 0; kb < 896; kb += 64) {
      int k0 = z * 896 + kb;
#pragma unroll
      for (int i = 0; i < 2; ++i) {
        int s = i * 256 + tid;
        int row = s >> 3, c = s & 7, kc = c ^ (row & 7);
        async_cp16(As + (size_t)s * 8, hidden + (size_t)(m0 + row) * 7168 + k0 + kc * 8);
      }
#pragma unroll
      for (int i = 0; i < 4; ++i) {
        int s = i * 256 + tid;
        int row = s >> 3, c = s & 7, kc = c ^ (row & 7);
        async_cp16(Bs + (size_t)s * 8, BT2 + (size_t)(n0 + row) * 7168 + k0 + kc * 8);
      }
      __syncthreads();
#pragma unroll
      for (int ksub = 0; ksub < 2; ++ksub) {
        bf16x8 af[2], bfm[4];
#pragma unroll
        for (int mt = 0; mt < 2; ++mt) {
          int r = mrow + mt * 16 + lo;
          af[mt] = *(const bf16x8*)(As + r * 64 + (((ksub * 4 + quad) ^ (r & 7)) * 8));
        }
#pragma unroll
        for (int nt = 0; nt < 4; ++nt) {
          int r = nrow + nt * 16 + lo;
          bfm[nt] = *(const bf16x8*)(Bs + r * 64 + (((ksub * 4 + quad) ^ (r & 7)) * 8));
        }
#pragma unroll
        for (int mt = 0; mt < 2; ++mt)
#pragma unroll
          for (int nt = 0; nt < 4; ++nt)
            acc[mt][nt] = __builtin_amdgcn_mfma_f32_16x16x32_bf16(af[mt], bfm[nt], acc[mt][nt], 0, 0, 0);
      }
      __syncthreads();
    }
    float* dst = part + (size_t)z * 262144;
#pragma unroll
    for (int mt = 0; mt < 2; ++mt)
#pragma unroll
      for (int nt = 0; nt < 4; ++nt)
#pragma unroll
        for (int r = 0; r < 4; ++r)
          dst[(size_t)(m0 + mrow + mt * 16 + quad * 4 + r) * 256 +
              (n0 + nrow + nt * 16 + lo)] = acc[mt][nt][r];
    return;
  }

  // -------- q GEMM: 64x128 tile, MX K=128, direct-global packed fragments ----
  int flat = blockIdx.x - 256;           // 1024; 256%8==0 keeps xcd = flat&7
  int xcd = flat & 7, lid = flat >> 3;
  int m0 = (lid & 15) * 64;
  int head = xcd * 8 + (lid >> 4);
  int n0 = head * 128;
  int mb0 = m0 >> 4, nb0 = n0 >> 4;
  int wm = wid & 1, wn = wid >> 1;
  int mrow = wm * 32, nrow = wn * 64;
  f32x4 zero4 = {0.f, 0.f, 0.f, 0.f};
  f32x4 acc[2][4];
#pragma unroll
  for (int a = 0; a < 2; ++a)
#pragma unroll
    for (int b = 0; b < 4; ++b) acc[a][b] = zero4;

  const unsigned char* pa = A + (size_t)(mb0 + wm * 2) * 24576 + lane * 16;
  const unsigned char* pb = B + (size_t)(nb0 + wn * 4) * 24576 + lane * 16;
  v8i av[2], bv[4], avn[2], bvn[4];
#pragma unroll
  for (int mt = 0; mt < 2; ++mt)
    av[mt] = cat8(*(const v4i*)(pa + (size_t)mt * 24576),
                  *(const v4i*)(pa + (size_t)mt * 24576 + 1024));
#pragma unroll
  for (int nt = 0; nt < 4; ++nt)
    bv[nt] = cat8(*(const v4i*)(pb + (size_t)nt * 24576),
                  *(const v4i*)(pb + (size_t)nt * 24576 + 1024));
  for (int k = 0; k < 12; ++k) {
    if (k < 11) {
      size_t ko = (size_t)(k + 1) * 2048;
#pragma unroll
      for (int mt = 0; mt < 2; ++mt)
        avn[mt] = cat8(*(const v4i*)(pa + (size_t)mt * 24576 + ko),
                       *(const v4i*)(pa + (size_t)mt * 24576 + ko + 1024));
#pragma unroll
      for (int nt = 0; nt < 4; ++nt)
        bvn[nt] = cat8(*(const v4i*)(pb + (size_t)nt * 24576 + ko),
                       *(const v4i*)(pb + (size_t)nt * 24576 + ko + 1024));
    }
#pragma unroll
    for (int mt = 0; mt < 2; ++mt)
#pragma unroll
      for (int nt = 0; nt < 4; ++nt)
        acc[mt][nt] = __builtin_amdgcn_mfma_scale_f32_16x16x128_f8f6f4(
            av[mt], bv[nt], acc[mt][nt], 0, 0, 0, SCL1, 0, SCL1);
#pragma unroll
    for (int mt = 0; mt < 2; ++mt) av[mt] = avn[mt];
#pragma unroll
    for (int nt = 0; nt < 4; ++nt) bv[nt] = bvn[nt];
  }
  // stage bf16 C tile (exact reference rounding point)
  u16* ct = (u16*)smem;
#pragma unroll
  for (int mt = 0; mt < 2; ++mt)
#pragma unroll
    for (int nt = 0; nt < 4; ++nt)
#pragma unroll
      for (int r = 0; r < 4; ++r)
        ct[(mrow + mt * 16 + quad * 4 + r) * 136 + (nrow + nt * 16 + lo)] =
            f2b(acc[mt][nt][r] * DEQ);
  __syncthreads();
  // fused planar epilogue: 8 half-waves x 8 rows; packed q_fp8 output
  int li = lane & 31, half = lane >> 5;
  int hw = wid * 2 + half;
  int qi = pk_u32_idx(head & 15, li) + (head >> 4) * 512;
#pragma unroll
  for (int i = 0; i < 8; ++i) {
    int r = hw * 8 + i;
    int t = m0 + r;
    u64 raw = *(const u64*)(ct + r * 136 + 4 * li);
    float v0 = b2f((u16)raw), v1 = b2f((u16)(raw >> 16));
    float v2 = b2f((u16)(raw >> 32)), v3 = b2f((u16)(raw >> 48));
    const float* csrow = cs + (size_t)positions[t] * 64;
    float4 c4 = make_float4(1.f, 1.f, 1.f, 1.f), s4 = make_float4(0.f, 0.f, 0.f, 0.f);
    if (li < 16) {
      c4 = *(const float4*)(csrow + 4 * (li & 7));
      s4 = *(const float4*)(csrow + 32 + 4 * (li & 7));
    }
    planar4(v0, v1, v2, v3, li, c4, s4,
            q_fp8 + (size_t)t * 2048 + qi, q_scale + t * 64 + head);
  }
}

// ------- k epilogue: fused 8-way reduce -> LN -> planar RoPE/FWHT/quant ------
__global__ __launch_bounds__(256) void k_epilogue(const float* __restrict__ kpart,
                                                  const float* __restrict__ knw,
                                                  const float* __restrict__ knb,
                                                  const float* __restrict__ cs,
                                                  const int* __restrict__ positions,
                                                  u32* __restrict__ k_fp8,
                                                  float* __restrict__ k_scale,
                                                  float* __restrict__ kaccw) {
  int wid = threadIdx.x >> 6, lane = threadIdx.x & 63;
  int li = lane & 31, half = lane >> 5;
  int t = blockIdx.x * 8 + wid * 2 + half;
  const float* base = kpart + (size_t)t * 256;
  float v0 = 0.f, v1 = 0.f, v2 = 0.f, v3 = 0.f, w0 = 0.f, w1 = 0.f;
#pragma unroll
  for (int z = 0; z < 8; ++z) {
    const float* p = base + (size_t)z * 262144;
    f32x4 kv = *(const f32x4*)(p + 4 * li);
    float2 wv = *(const float2*)(p + 128 + 2 * li);
    v0 += kv.x; v1 += kv.y; v2 += kv.z; v3 += kv.w;
    w0 += wv.x; w1 += wv.y;
  }
  *(float2*)(kaccw + (size_t)t * 64 + 2 * li) = make_float2(w0, w1);
  v0 = bfr(v0); v1 = bfr(v1); v2 = bfr(v2); v3 = bfr(v3);
  float sm = v0 + v1 + v2 + v3;
  float sq = v0 * v0 + v1 * v1 + v2 * v2 + v3 * v3;
#pragma unroll
  for (int m = 1; m <= 16; m <<= 1) {
    sm += __shfl_xor(sm, m, 64);
    sq += __shfl_xor(sq, m, 64);
  }
  float mean = sm * (1.0f / 128.0f);
  float var = sq * (1.0f / 128.0f) - mean * mean;
  float rstd = rsqrtf(var + 1e-6f);
  f32x4 g = *(const f32x4*)(knw + 4 * li);
  f32x4 bb = *(const f32x4*)(knb + 4 * li);
  v0 = bfr((v0 - mean) * rstd * g.x + bb.x);
  v1 = bfr((v1 - mean) * rstd * g.y + bb.y);
  v2 = bfr((v2 - mean) * rstd * g.z + bb.z);
  v3 = bfr((v3 - mean) * rstd * g.w + bb.w);
  const float* csrow = cs + (size_t)positions[t] * 64;
  float4 c4 = make_float4(1.f, 1.f, 1.f, 1.f), s4 = make_float4(0.f, 0.f, 0.f, 0.f);
  if (li < 16) {
    c4 = *(const float4*)(csrow + 4 * (li & 7));
    s4 = *(const float4*)(csrow + 32 + 4 * (li & 7));
  }
  planar4(v0, v1, v2, v3, li, c4, s4,
          k_fp8 + (size_t)(t >> 4) * 512 + pk_u32_idx(t & 15, li), k_scale + t);
}

// ------- scores+logits+mask+idx: MX-scaled K=128, packed operands ------------
__global__ __launch_bounds__(256) void scores_kernel(const unsigned char* __restrict__ q_fp8,
                                                     const unsigned char* __restrict__ k_fp8,
                                                     const float* __restrict__ q_scale,
                                                     const float* __restrict__ k_scale,
                                                     const float* __restrict__ kaccw,
                                                     const int* __restrict__ positions,
                                                     float* __restrict__ out) {
  __shared__ unsigned char kt[16384];
  __shared__ float wfinL[256];
  __shared__ float ksL[128];
  int flat = blockIdx.x, tid = threadIdx.x;
  int jt0 = flat >> 8, g = flat & 255;
  int t0 = 4 * g, j0 = 128 * jt0;
  float* logits = out + (size_t)1048576;
#pragma unroll
  for (int e = 0; e < 2; ++e) {
    int ent = e * 256 + tid;
    int tt = t0 + (ent >> 7), j = j0 + (ent & 127);
    out[(size_t)tt * 1024 + j] = (j <= positions[tt]) ? (float)j : -1.0f;
  }
  if (j0 > t0 + 3) {  // fully-masked tile: logits = NEG
#pragma unroll
    for (int e = 0; e < 2; ++e) {
      int ent = e * 256 + tid;
      int tt = t0 + (ent >> 7), j = j0 + (ent & 127);
      logits[(size_t)tt * 1024 + j] = NEGF;
    }
    return;
  }
#pragma unroll
  for (int i = 0; i < 4; ++i)            // stage k tile: pure linear 16 KB copy
    async_cp16(kt + (size_t)(i * 256 + tid) * 16,
               k_fp8 + (size_t)j0 * 128 + (size_t)(i * 256 + tid) * 16);
  {
    int tl = tid >> 6, h = tid & 63;
    wfinL[tid] = kaccw[(size_t)(t0 + tl) * 64 + h] *
                 q_scale[(size_t)(t0 + tl) * 64 + h] * WCONST;
  }
  if (tid < 128) ksL[tid] = k_scale[j0 + tid];
  int wid = tid >> 6, lane = tid & 63, lo = lane & 15, quad = lane >> 4;
  int t = t0 + wid;
  int pt = positions[t];
  v8i a8[4];
  const unsigned char* qbase = q_fp8 + (size_t)t * 8192;
#pragma unroll
  for (int ht = 0; ht < 4; ++ht) {
    v4i l0 = *(const v4i*)(qbase + ht * 2048 + lane * 16);
    v4i h0 = *(const v4i*)(qbase + ht * 2048 + 1024 + lane * 16);
    a8[ht] = cat8(l0, h0);
  }
  __syncthreads();
  float wf[4][4];
#pragma unroll
  for (int ht = 0; ht < 4; ++ht)
#pragma unroll
    for (int r = 0; r < 4; ++r) wf[ht][r] = wfinL[wid * 64 + ht * 16 + quad * 4 + r];
  f32x4 zero4 = {0.f, 0.f, 0.f, 0.f};
#pragma unroll
  for (int jc = 0; jc < 2; ++jc) {
    f32x4 acc[4][4];
#pragma unroll
    for (int ht = 0; ht < 4; ++ht)
#pragma unroll
      for (int jt = 0; jt < 4; ++jt) acc[ht][jt] = zero4;
    v8i bv[4];
#pragma unroll
    for (int jt = 0; jt < 4; ++jt) {
      v4i l0 = *(const v4i*)(kt + (jc * 4 + jt) * 2048 + lane * 16);
      v4i h0 = *(const v4i*)(kt + (jc * 4 + jt) * 2048 + 1024 + lane * 16);
      bv[jt] = cat8(l0, h0);
    }
#pragma unroll
    for (int ht = 0; ht < 4; ++ht)
#pragma unroll
      for (int jt = 0; jt < 4; ++jt)
        acc[ht][jt] = __builtin_amdgcn_mfma_scale_f32_16x16x128_f8f6f4(
            a8[ht], bv[jt], acc[ht][jt], 0, 0, 0, SCL1, 0, SCL1);
#pragma unroll
    for (int jt = 0; jt < 4; ++jt) {
      float v = 0.f;
#pragma unroll
      for (int ht = 0; ht < 4; ++ht)
#pragma unroll
        for (int r = 0; r < 4; ++r)
          v += fmaxf(acc[ht][jt][r], 0.f) * wf[ht][r];
      v += __shfl_xor(v, 16, 64);
      v += __shfl_xor(v, 32, 64);
      int jloc = jc * 64 + jt * 16 + lo;
      int j = j0 + jloc;
      if (quad == 0)
        logits[(size_t)t * 1024 + j] = (j <= pt) ? v * ksL[jloc] : NEGF;
    }
  }
}

// ---------------------------------------------------------------------------
extern "C" void kernel_launch(void* const* d_in, const int* in_sizes, int n_in,
                              void* d_out, int out_size, void* d_ws, size_t ws_size,
                              hipStream_t stream) {
  const u16* hidden = (const u16*)d_in[0];   // (1024,7168) bf16
  const u16* q_lora = (const u16*)d_in[1];   // (1024,1536) bf16
  const u16* wq_b   = (const u16*)d_in[2];   // (1536,8192) bf16
  const u16* wk     = (const u16*)d_in[3];   // (7168,128) bf16
  const float* knw  = (const float*)d_in[4]; // (128,)
  const float* knb  = (const float*)d_in[5]; // (128,)
  const float* wproj= (const float*)d_in[6]; // (7168,64) f32
  const float* cs   = (const float*)d_in[7]; // (1024,64) f32
  const int* pos    = (const int*)d_in[8];   // (1024,)
  float* out = (float*)d_out;                // [idx-as-float 1M | logits 1M]

  char* ws = (char*)d_ws;
  u16* BT2            = (u16*)(ws);                      // 256x7168 bf16   = 3,670,016
  float* kpart        = (float*)(ws + 3670016);          // 8x1024x256 f32  = 8,388,608
  float* kaccw        = (float*)(ws + 20447232);         // 1024x64 f32     = 262,144
  unsigned char* wq8  = (unsigned char*)(ws + 20709376); // packed fp8      = 12,582,912
  unsigned char* aq8  = (unsigned char*)(ws + 33292288); // packed fp8      = 1,572,864
  unsigned char* qf8  = (unsigned char*)(ws + 34865152); // packed fp8      = 8,388,608
  float* qsc          = (float*)(ws + 43253760);         // 65536 f32       = 262,144
  unsigned char* kf8  = (unsigned char*)(ws + 43515904); // packed fp8      = 131,072
  float* ksc          = (float*)(ws + 43646976);         // 1024 f32        = 4,096

  prep_transpose<<<3872, 256, 0, stream>>>(wq_b, wk, wproj, q_lora, wq8, aq8, BT2);

  // merged: k/w GEMM first (long blocks), then q GEMM (MX fp8, no-LDS loop)
  gemm_merged<<<1280, 256, 0, stream>>>(aq8, wq8, cs, pos, (u32*)qf8, qsc,
                                        hidden, BT2, kpart);
  k_epilogue<<<128, 256, 0, stream>>>(kpart, knw, knb, cs, pos, (u32*)kf8, ksc, kaccw);

  // logits + causal mask + idx output, MX-scaled
  scores_kernel<<<2048, 256, 0, stream>>>(qf8, kf8, qsc, ksc, kaccw, pos, out);

  (void)in_sizes; (void)n_in; (void)out_size; (void)ws_size;
}

// Round 11
// 179.067 us; speedup vs baseline: 1.0676x; 1.0676x over previous
//
#include <hip/hip_runtime.h>

typedef unsigned short u16;
typedef unsigned int u32;
typedef unsigned long long u64;
typedef __bf16 bf16x8 __attribute__((ext_vector_type(8)));
typedef float f32x4 __attribute__((ext_vector_type(4)));
typedef unsigned short ushort8 __attribute__((ext_vector_type(8)));
typedef int v4i __attribute__((ext_vector_type(4)));
typedef int v8i __attribute__((ext_vector_type(8)));

#define NEGF (-1e30f)
#define HAD_SCALE 0.08838834764831845f   // 128^-0.5
#define WCONST 0.011048543456039806f     // 128^-0.5 * 64^-0.5
#define SA 64.0f                          // q_lora fp8 scale
#define SB 1024.0f                        // wq_b fp8 scale
#define DEQ (1.0f / 65536.0f)             // 1/(SA*SB)
#define SCL1 0x7f7f7f7f                   // e8m0 scale = 1.0 in every byte

__device__ __forceinline__ float b2f(u16 u) {
  union { u32 i; float f; } x; x.i = ((u32)u) << 16; return x.f;
}
__device__ __forceinline__ u16 f2b(float f) {  // RNE f32->bf16
  u32 u = __float_as_uint(f);
  return (u16)((u + 0x7fffu + ((u >> 16) & 1u)) >> 16);
}
__device__ __forceinline__ float bfr(float f) { return b2f(f2b(f)); }

__device__ __forceinline__ void async_cp16(void* lds, const void* g) {
  __builtin_amdgcn_global_load_lds((__attribute__((address_space(1))) void*)g,
                                   (__attribute__((address_space(3))) void*)lds, 16, 0, 0);
}

__device__ __forceinline__ u32 pk4_fp8(float a, float b, float c, float d) {
  u32 w = (u32)__builtin_amdgcn_cvt_pk_fp8_f32(a, b, 0, false);
  w = (u32)__builtin_amdgcn_cvt_pk_fp8_f32(c, d, (int)w, true);
  return w;
}

__device__ __forceinline__ v8i cat8(v4i lo, v4i hi) {
  return __builtin_shufflevector(lo, hi, 0, 1, 2, 3, 4, 5, 6, 7);
}

// Packed-fragment layout (16-row blocks) — unchanged from round 8.
__device__ __forceinline__ size_t pk_granule(int r4, int k) {
  return (size_t)((k >> 6) * 1024 + (((k >> 3) & 3) * 16 + r4) * 16 + (((k >> 5) & 1) * 8));
}
__device__ __forceinline__ int pk_u32_idx(int r4, int li) {
  return (li >> 4) * 256 + (((li >> 1) & 3) * 16 + r4) * 4 + ((li >> 3) & 1) * 2 + (li & 1);
}

// ---------------- bf16 tile transpose (wk / wproj -> BT2) --------------------
__device__ __forceinline__ void tr_tile(const void* src, u16* dst, int Nn,
                                        int dpitch, int f32src, int k0, int n0,
                                        u16* tl) {
  int tid = threadIdx.x;
  int kk = tid >> 3, nc = tid & 7;
  u16 v[8];
  if (f32src) {
    const float* s = (const float*)src + (size_t)(k0 + kk) * Nn + n0 + nc * 8;
#pragma unroll
    for (int j = 0; j < 8; ++j) v[j] = f2b(s[j]);
  } else {
    const u16* s = (const u16*)src + (size_t)(k0 + kk) * Nn + n0 + nc * 8;
    ushort8 x = *(const ushort8*)s;
#pragma unroll
    for (int j = 0; j < 8; ++j) v[j] = x[j];
  }
#pragma unroll
  for (int j = 0; j < 8; ++j) tl[(nc * 8 + j) * 56 + kk] = v[j];
  __syncthreads();
  int n = tid >> 2, kc = tid & 3;
  ushort8 o = *(const ushort8*)(tl + n * 56 + kc * 8);
  *(ushort8*)(dst + (size_t)(n0 + n) * dpitch + k0 + kc * 8) = o;
}

// ------- prep: wq_b -> wq8 (fp8 packed), q_lora -> aq8 (fp8 packed), BT2 -----
__global__ __launch_bounds__(256) void prep_transpose(const u16* __restrict__ wq_b,
                                                      const u16* __restrict__ wk,
                                                      const float* __restrict__ wproj,
                                                      const u16* __restrict__ q_lora,
                                                      unsigned char* __restrict__ wq8,
                                                      unsigned char* __restrict__ aq8,
                                                      u16* __restrict__ BT2) {
  __shared__ u16 tl[64 * 72];
  int b = blockIdx.x, tid = threadIdx.x;
  if (b < 3072) {        // wq_b (1536,8192) -> wq8 packed, tile 64k x 64n
    int kt0 = (b % 24) * 64, n0 = (b / 24) * 64;
#pragma unroll
    for (int i = 0; i < 2; ++i) {
      int s = i * 256 + tid;
      int row = s >> 3, c = s & 7;
      ushort8 x = *(const ushort8*)(wq_b + (size_t)(kt0 + row) * 8192 + n0 + c * 8);
#pragma unroll
      for (int j = 0; j < 8; ++j) tl[(c * 8 + j) * 72 + row] = x[j];
    }
    __syncthreads();
    int n = tid >> 2, kc = tid & 3;
    const u16* src = tl + n * 72 + kc * 16;
    u32 w[4];
#pragma unroll
    for (int g = 0; g < 4; ++g)
      w[g] = pk4_fp8(b2f(src[4 * g]) * SB, b2f(src[4 * g + 1]) * SB,
                     b2f(src[4 * g + 2]) * SB, b2f(src[4 * g + 3]) * SB);
    int gn = n0 + n;
    int k1 = kt0 + kc * 16;
    size_t ga = (size_t)(gn >> 4) * 24576 + pk_granule(gn & 15, k1);
    *(u64*)(wq8 + ga) = (u64)w[0] | ((u64)w[1] << 32);
    *(u64*)(wq8 + ga + 256) = (u64)w[2] | ((u64)w[3] << 32);
  } else if (b < 3520) { // wk (7168,128) -> BT2 rows 0..127
    int g = b - 3072;
    tr_tile(wk, BT2, 128, 7168, 0, (g % 224) * 32, (g / 224) * 64, tl);
  } else if (b < 3744) { // wproj (7168,64) f32 -> BT2 rows 128..191
    int g = b - 3520;
    tr_tile(wproj, BT2 + (size_t)128 * 7168, 64, 7168, 1, g * 32, 0, tl);
  } else if (b < 3808) { // zero BT2 rows 192..255
    int r = 192 + (b - 3744);
    ushort8 z = {0, 0, 0, 0, 0, 0, 0, 0};
    u16* row = BT2 + (size_t)r * 7168;
    for (int i = tid; i < 896; i += 256) *(ushort8*)(row + i * 8) = z;
  } else {               // q_lora (1024,1536) -> aq8 packed
    int mb = b - 3808;
#pragma unroll
    for (int it = 0; it < 6; ++it) {
      int id = it * 256 + tid;
      int c = id >> 4, r = id & 15;
      const u16* src = q_lora + (size_t)(mb * 16 + r) * 1536 + c * 16;
      ushort8 x0 = *(const ushort8*)src;
      ushort8 x1 = *(const ushort8*)(src + 8);
      u32 w0 = pk4_fp8(b2f(x0[0]) * SA, b2f(x0[1]) * SA, b2f(x0[2]) * SA, b2f(x0[3]) * SA);
      u32 w1 = pk4_fp8(b2f(x0[4]) * SA, b2f(x0[5]) * SA, b2f(x0[6]) * SA, b2f(x0[7]) * SA);
      u32 w2 = pk4_fp8(b2f(x1[0]) * SA, b2f(x1[1]) * SA, b2f(x1[2]) * SA, b2f(x1[3]) * SA);
      u32 w3 = pk4_fp8(b2f(x1[4]) * SA, b2f(x1[5]) * SA, b2f(x1[6]) * SA, b2f(x1[7]) * SA);
      size_t ga = (size_t)mb * 24576 + pk_granule(r, c * 16);
      *(u64*)(aq8 + ga) = (u64)w0 | ((u64)w1 << 32);
      *(u64*)(aq8 + ga + 256) = (u64)w2 | ((u64)w3 << 32);
    }
  }
}

// ------- planar-4 row op: RoPE -> FWHT-128 -> fp8 quant ----------------------
__device__ __forceinline__ void planar4(float v0, float v1, float v2, float v3,
                                        int li, float4 c4, float4 s4,
                                        u32* __restrict__ dst_word,
                                        float* __restrict__ dstscale) {
  float p0 = __shfl_xor(v0, 8, 64);
  float p1 = __shfl_xor(v1, 8, 64);
  float p2 = __shfl_xor(v2, 8, 64);
  float p3 = __shfl_xor(v3, 8, 64);
  if (li < 8) {
    v0 = bfr(v0 * c4.x - p0 * s4.x); v1 = bfr(v1 * c4.y - p1 * s4.y);
    v2 = bfr(v2 * c4.z - p2 * s4.z); v3 = bfr(v3 * c4.w - p3 * s4.w);
  } else if (li < 16) {
    v0 = bfr(v0 * c4.x + p0 * s4.x); v1 = bfr(v1 * c4.y + p1 * s4.y);
    v2 = bfr(v2 * c4.z + p2 * s4.z); v3 = bfr(v3 * c4.w + p3 * s4.w);
  }
  { float a = v0 + v1, b = v0 - v1; v0 = a; v1 = b; }
  { float a = v2 + v3, b = v2 - v3; v2 = a; v3 = b; }
  { float a = v0 + v2, b = v0 - v2; v0 = a; v2 = b; }
  { float a = v1 + v3, b = v1 - v3; v1 = a; v3 = b; }
#pragma unroll
  for (int m = 1; m <= 16; m <<= 1) {
    float q0 = __shfl_xor(v0, m, 64), q1 = __shfl_xor(v1, m, 64);
    float q2 = __shfl_xor(v2, m, 64), q3 = __shfl_xor(v3, m, 64);
    if (li & m) { v0 = q0 - v0; v1 = q1 - v1; v2 = q2 - v2; v3 = q3 - v3; }
    else        { v0 += q0;     v1 += q1;     v2 += q2;     v3 += q3; }
  }
  v0 = bfr(v0 * HAD_SCALE); v1 = bfr(v1 * HAD_SCALE);
  v2 = bfr(v2 * HAD_SCALE); v3 = bfr(v3 * HAD_SCALE);
  float am = fmaxf(fmaxf(fabsf(v0), fabsf(v1)), fmaxf(fabsf(v2), fabsf(v3)));
#pragma unroll
  for (int m = 1; m <= 16; m <<= 1) am = fmaxf(am, __shfl_xor(am, m, 64));
  am = fmaxf(am, 1e-4f);
  float scale = am / 448.0f;
  float inv = 1.0f / scale;
  *dst_word = pk4_fp8(v0 * inv, v1 * inv, v2 * inv, v3 * inv);
  if (li == 0) *dstscale = scale;
}

// ======== merged: [blk<512] k/w GEMM split-K=16 (bf16, dispatched FIRST) =====
// ======== [blk>=512] q GEMM (MX fp8 K=128, LDS-staged) + fused epilogue ======
__global__ __launch_bounds__(256) void gemm_merged(const unsigned char* __restrict__ A,
                                                   const unsigned char* __restrict__ B,
                                                   const float* __restrict__ cs,
                                                   const int* __restrict__ positions,
                                                   u32* __restrict__ q_fp8,
                                                   float* __restrict__ q_scale,
                                                   const u16* __restrict__ hidden,
                                                   const u16* __restrict__ BT2,
                                                   float* __restrict__ part) {
  __shared__ unsigned char smem[24576];
  int tid = threadIdx.x, wid = tid >> 6, lane = tid & 63, lo = lane & 15, quad = lane >> 4;

  if (blockIdx.x < 512) {
    // ---------------- k/w GEMM: 64x128 tile, BK=64, split-K=16 ---------------
    u16* As = (u16*)smem;
    u16* Bs = (u16*)smem + 4096;
    int flat = blockIdx.x;               // xcd owns z-slices {z&7 == xcd}
    int zlo = flat & 7, up = flat >> 3;
    int m = up & 15, n = (up >> 4) & 1, zhi = up >> 5;
    int z = zlo + 8 * zhi;
    int m0 = m * 64, n0 = n * 128;
    int mrow = (wid & 1) * 32, nrow = (wid >> 1) * 64;
    f32x4 zero4 = {0.f, 0.f, 0.f, 0.f};
    f32x4 acc[2][4];
#pragma unroll
    for (int a = 0; a < 2; ++a)
#pragma unroll
      for (int b = 0; b < 4; ++b) acc[a][b] = zero4;
    for (int kb = 0; kb < 448; kb += 64) {
      int k0 = z * 448 + kb;
#pragma unroll
      for (int i = 0; i < 2; ++i) {
        int s = i * 256 + tid;
        int row = s >> 3, c = s & 7, kc = c ^ (row & 7);
        async_cp16(As + (size_t)s * 8, hidden + (size_t)(m0 + row) * 7168 + k0 + kc * 8);
      }
#pragma unroll
      for (int i = 0; i < 4; ++i) {
        int s = i * 256 + tid;
        int row = s >> 3, c = s & 7, kc = c ^ (row & 7);
        async_cp16(Bs + (size_t)s * 8, BT2 + (size_t)(n0 + row) * 7168 + k0 + kc * 8);
      }
      __syncthreads();
#pragma unroll
      for (int ksub = 0; ksub < 2; ++ksub) {
        bf16x8 af[2], bfm[4];
#pragma unroll
        for (int mt = 0; mt < 2; ++mt) {
          int r = mrow + mt * 16 + lo;
          af[mt] = *(const bf16x8*)(As + r * 64 + (((ksub * 4 + quad) ^ (r & 7)) * 8));
        }
#pragma unroll
        for (int nt = 0; nt < 4; ++nt) {
          int r = nrow + nt * 16 + lo;
          bfm[nt] = *(const bf16x8*)(Bs + r * 64 + (((ksub * 4 + quad) ^ (r & 7)) * 8));
        }
#pragma unroll
        for (int mt = 0; mt < 2; ++mt)
#pragma unroll
          for (int nt = 0; nt < 4; ++nt)
            acc[mt][nt] = __builtin_amdgcn_mfma_f32_16x16x32_bf16(af[mt], bfm[nt], acc[mt][nt], 0, 0, 0);
      }
      __syncthreads();
    }
    float* dst = part + (size_t)z * 262144;
#pragma unroll
    for (int mt = 0; mt < 2; ++mt)
#pragma unroll
      for (int nt = 0; nt < 4; ++nt)
#pragma unroll
        for (int r = 0; r < 4; ++r)
          dst[(size_t)(m0 + mrow + mt * 16 + quad * 4 + r) * 256 +
              (n0 + nrow + nt * 16 + lo)] = acc[mt][nt][r];
    return;
  }

  // -------- q GEMM: 64x128 tile, MX K=128, LDS-staged packed fragments -------
  unsigned char* As = smem;
  unsigned char* Bs = smem + 8192;
  int flat = blockIdx.x - 512;           // 1024; 512%8==0 keeps xcd = flat&7
  int xcd = flat & 7, lid = flat >> 3;
  int m0 = (lid & 15) * 64;
  int head = xcd * 8 + (lid >> 4);
  int n0 = head * 128;
  int mb0 = m0 >> 4, nb0 = n0 >> 4;
  int wm = wid & 1, wn = wid >> 1;
  int mrow = wm * 32, nrow = wn * 64;
  f32x4 zero4 = {0.f, 0.f, 0.f, 0.f};
  f32x4 acc[2][4];
#pragma unroll
  for (int a = 0; a < 2; ++a)
#pragma unroll
    for (int b = 0; b < 4; ++b) acc[a][b] = zero4;

  for (int k0 = 0; k0 < 1536; k0 += 128) {
    int pg0 = k0 >> 6;
#pragma unroll
    for (int i = 0; i < 2; ++i) {        // A: 8 units of 1KB, lane-linear
      int s = i * 256 + tid;
      int u = s >> 6, l64 = s & 63;
      async_cp16(As + (size_t)s * 16,
                 A + (size_t)(mb0 + (u >> 1)) * 24576 + (size_t)(pg0 + (u & 1)) * 1024 + l64 * 16);
    }
#pragma unroll
    for (int i = 0; i < 4; ++i) {        // B: 16 units of 1KB
      int s = i * 256 + tid;
      int u = s >> 6, l64 = s & 63;
      async_cp16(Bs + (size_t)s * 16,
                 B + (size_t)(nb0 + (u >> 1)) * 24576 + (size_t)(pg0 + (u & 1)) * 1024 + l64 * 16);
    }
    __syncthreads();
    v8i av[2], bv[4];
#pragma unroll
    for (int mt = 0; mt < 2; ++mt) {
      v4i l0 = *(const v4i*)(As + ((wm * 2 + mt) * 2 + 0) * 1024 + lane * 16);
      v4i h0 = *(const v4i*)(As + ((wm * 2 + mt) * 2 + 1) * 1024 + lane * 16);
      av[mt] = cat8(l0, h0);
    }
#pragma unroll
    for (int nt = 0; nt < 4; ++nt) {
      v4i l0 = *(const v4i*)(Bs + ((wn * 4 + nt) * 2 + 0) * 1024 + lane * 16);
      v4i h0 = *(const v4i*)(Bs + ((wn * 4 + nt) * 2 + 1) * 1024 + lane * 16);
      bv[nt] = cat8(l0, h0);
    }
#pragma unroll
    for (int mt = 0; mt < 2; ++mt)
#pragma unroll
      for (int nt = 0; nt < 4; ++nt)
        acc[mt][nt] = __builtin_amdgcn_mfma_scale_f32_16x16x128_f8f6f4(
            av[mt], bv[nt], acc[mt][nt], 0, 0, 0, SCL1, 0, SCL1);
    __syncthreads();
  }
  // stage bf16 C tile (exact reference rounding point)
  u16* ct = (u16*)smem;
#pragma unroll
  for (int mt = 0; mt < 2; ++mt)
#pragma unroll
    for (int nt = 0; nt < 4; ++nt)
#pragma unroll
      for (int r = 0; r < 4; ++r)
        ct[(mrow + mt * 16 + quad * 4 + r) * 136 + (nrow + nt * 16 + lo)] =
            f2b(acc[mt][nt][r] * DEQ);
  __syncthreads();
  // fused planar epilogue: 8 half-waves x 8 rows; packed q_fp8 output
  int li = lane & 31, half = lane >> 5;
  int hw = wid * 2 + half;
  int qi = pk_u32_idx(head & 15, li) + (head >> 4) * 512;
#pragma unroll
  for (int i = 0; i < 8; ++i) {
    int r = hw * 8 + i;
    int t = m0 + r;
    u64 raw = *(const u64*)(ct + r * 136 + 4 * li);
    float v0 = b2f((u16)raw), v1 = b2f((u16)(raw >> 16));
    float v2 = b2f((u16)(raw >> 32)), v3 = b2f((u16)(raw >> 48));
    const float* csrow = cs + (size_t)positions[t] * 64;
    float4 c4 = make_float4(1.f, 1.f, 1.f, 1.f), s4 = make_float4(0.f, 0.f, 0.f, 0.f);
    if (li < 16) {
      c4 = *(const float4*)(csrow + 4 * (li & 7));
      s4 = *(const float4*)(csrow + 32 + 4 * (li & 7));
    }
    planar4(v0, v1, v2, v3, li, c4, s4,
            q_fp8 + (size_t)t * 2048 + qi, q_scale + t * 64 + head);
  }
}

// ------- k epilogue: fused 16-way reduce -> LN -> planar RoPE/FWHT/quant -----
__global__ __launch_bounds__(256) void k_epilogue(const float* __restrict__ kpart,
                                                  const float* __restrict__ knw,
                                                  const float* __restrict__ knb,
                                                  const float* __restrict__ cs,
                                                  const int* __restrict__ positions,
                                                  u32* __restrict__ k_fp8,
                                                  float* __restrict__ k_scale,
                                                  float* __restrict__ kaccw) {
  int wid = threadIdx.x >> 6, lane = threadIdx.x & 63;
  int li = lane & 31, half = lane >> 5;
  int t = blockIdx.x * 8 + wid * 2 + half;
  const float* base = kpart + (size_t)t * 256;
  float v0 = 0.f, v1 = 0.f, v2 = 0.f, v3 = 0.f, w0 = 0.f, w1 = 0.f;
#pragma unroll
  for (int z = 0; z < 16; ++z) {
    const float* p = base + (size_t)z * 262144;
    f32x4 kv = *(const f32x4*)(p + 4 * li);
    float2 wv = *(const float2*)(p + 128 + 2 * li);
    v0 += kv.x; v1 += kv.y; v2 += kv.z; v3 += kv.w;
    w0 += wv.x; w1 += wv.y;
  }
  *(float2*)(kaccw + (size_t)t * 64 + 2 * li) = make_float2(w0, w1);
  v0 = bfr(v0); v1 = bfr(v1); v2 = bfr(v2); v3 = bfr(v3);
  float sm = v0 + v1 + v2 + v3;
  float sq = v0 * v0 + v1 * v1 + v2 * v2 + v3 * v3;
#pragma unroll
  for (int m = 1; m <= 16; m <<= 1) {
    sm += __shfl_xor(sm, m, 64);
    sq += __shfl_xor(sq, m, 64);
  }
  float mean = sm * (1.0f / 128.0f);
  float var = sq * (1.0f / 128.0f) - mean * mean;
  float rstd = rsqrtf(var + 1e-6f);
  f32x4 g = *(const f32x4*)(knw + 4 * li);
  f32x4 bb = *(const f32x4*)(knb + 4 * li);
  v0 = bfr((v0 - mean) * rstd * g.x + bb.x);
  v1 = bfr((v1 - mean) * rstd * g.y + bb.y);
  v2 = bfr((v2 - mean) * rstd * g.z + bb.z);
  v3 = bfr((v3 - mean) * rstd * g.w + bb.w);
  const float* csrow = cs + (size_t)positions[t] * 64;
  float4 c4 = make_float4(1.f, 1.f, 1.f, 1.f), s4 = make_float4(0.f, 0.f, 0.f, 0.f);
  if (li < 16) {
    c4 = *(const float4*)(csrow + 4 * (li & 7));
    s4 = *(const float4*)(csrow + 32 + 4 * (li & 7));
  }
  planar4(v0, v1, v2, v3, li, c4, s4,
          k_fp8 + (size_t)(t >> 4) * 512 + pk_u32_idx(t & 15, li), k_scale + t);
}

// ------- scores+logits+mask+idx: MX-scaled K=128, packed operands ------------
__global__ __launch_bounds__(256) void scores_kernel(const unsigned char* __restrict__ q_fp8,
                                                     const unsigned char* __restrict__ k_fp8,
                                                     const float* __restrict__ q_scale,
                                                     const float* __restrict__ k_scale,
                                                     const float* __restrict__ kaccw,
                                                     const int* __restrict__ positions,
                                                     float* __restrict__ out) {
  __shared__ unsigned char kt[16384];
  __shared__ float wfinL[256];
  __shared__ float ksL[128];
  int flat = blockIdx.x, tid = threadIdx.x;
  int jt0 = flat >> 8, g = flat & 255;
  int t0 = 4 * g, j0 = 128 * jt0;
  float* logits = out + (size_t)1048576;
#pragma unroll
  for (int e = 0; e < 2; ++e) {
    int ent = e * 256 + tid;
    int tt = t0 + (ent >> 7), j = j0 + (ent & 127);
    out[(size_t)tt * 1024 + j] = (j <= positions[tt]) ? (float)j : -1.0f;
  }
  if (j0 > t0 + 3) {  // fully-masked tile: logits = NEG
#pragma unroll
    for (int e = 0; e < 2; ++e) {
      int ent = e * 256 + tid;
      int tt = t0 + (ent >> 7), j = j0 + (ent & 127);
      logits[(size_t)tt * 1024 + j] = NEGF;
    }
    return;
  }
#pragma unroll
  for (int i = 0; i < 4; ++i)            // stage k tile: pure linear 16 KB copy
    async_cp16(kt + (size_t)(i * 256 + tid) * 16,
               k_fp8 + (size_t)j0 * 128 + (size_t)(i * 256 + tid) * 16);
  {
    int tl = tid >> 6, h = tid & 63;
    wfinL[tid] = kaccw[(size_t)(t0 + tl) * 64 + h] *
                 q_scale[(size_t)(t0 + tl) * 64 + h] * WCONST;
  }
  if (tid < 128) ksL[tid] = k_scale[j0 + tid];
  int wid = tid >> 6, lane = tid & 63, lo = lane & 15, quad = lane >> 4;
  int t = t0 + wid;
  int pt = positions[t];
  v8i a8[4];
  const unsigned char* qbase = q_fp8 + (size_t)t * 8192;
#pragma unroll
  for (int ht = 0; ht < 4; ++ht) {
    v4i l0 = *(const v4i*)(qbase + ht * 2048 + lane * 16);
    v4i h0 = *(const v4i*)(qbase + ht * 2048 + 1024 + lane * 16);
    a8[ht] = cat8(l0, h0);
  }
  __syncthreads();
  float wf[4][4];
#pragma unroll
  for (int ht = 0; ht < 4; ++ht)
#pragma unroll
    for (int r = 0; r < 4; ++r) wf[ht][r] = wfinL[wid * 64 + ht * 16 + quad * 4 + r];
  f32x4 zero4 = {0.f, 0.f, 0.f, 0.f};
#pragma unroll
  for (int jc = 0; jc < 2; ++jc) {
    f32x4 acc[4][4];
#pragma unroll
    for (int ht = 0; ht < 4; ++ht)
#pragma unroll
      for (int jt = 0; jt < 4; ++jt) acc[ht][jt] = zero4;
    v8i bv[4];
#pragma unroll
    for (int jt = 0; jt < 4; ++jt) {
      v4i l0 = *(const v4i*)(kt + (jc * 4 + jt) * 2048 + lane * 16);
      v4i h0 = *(const v4i*)(kt + (jc * 4 + jt) * 2048 + 1024 + lane * 16);
      bv[jt] = cat8(l0, h0);
    }
#pragma unroll
    for (int ht = 0; ht < 4; ++ht)
#pragma unroll
      for (int jt = 0; jt < 4; ++jt)
        acc[ht][jt] = __builtin_amdgcn_mfma_scale_f32_16x16x128_f8f6f4(
            a8[ht], bv[jt], acc[ht][jt], 0, 0, 0, SCL1, 0, SCL1);
#pragma unroll
    for (int jt = 0; jt < 4; ++jt) {
      float v = 0.f;
#pragma unroll
      for (int ht = 0; ht < 4; ++ht)
#pragma unroll
        for (int r = 0; r < 4; ++r)
          v += fmaxf(acc[ht][jt][r], 0.f) * wf[ht][r];
      v += __shfl_xor(v, 16, 64);
      v += __shfl_xor(v, 32, 64);
      int jloc = jc * 64 + jt * 16 + lo;
      int j = j0 + jloc;
      if (quad == 0)
        logits[(size_t)t * 1024 + j] = (j <= pt) ? v * ksL[jloc] : NEGF;
    }
  }
}

// ---------------------------------------------------------------------------
extern "C" void kernel_launch(void* const* d_in, const int* in_sizes, int n_in,
                              void* d_out, int out_size, void* d_ws, size_t ws_size,
                              hipStream_t stream) {
  const u16* hidden = (const u16*)d_in[0];   // (1024,7168) bf16
  const u16* q_lora = (const u16*)d_in[1];   // (1024,1536) bf16
  const u16* wq_b   = (const u16*)d_in[2];   // (1536,8192) bf16
  const u16* wk     = (const u16*)d_in[3];   // (7168,128) bf16
  const float* knw  = (const float*)d_in[4]; // (128,)
  const float* knb  = (const float*)d_in[5]; // (128,)
  const float* wproj= (const float*)d_in[6]; // (7168,64) f32
  const float* cs   = (const float*)d_in[7]; // (1024,64) f32
  const int* pos    = (const int*)d_in[8];   // (1024,)
  float* out = (float*)d_out;                // [idx-as-float 1M | logits 1M]

  char* ws = (char*)d_ws;
  u16* BT2            = (u16*)(ws);                      // 256x7168 bf16   = 3,670,016
  float* kpart        = (float*)(ws + 3670016);          // 16x1024x256 f32 = 16,777,216
  float* kaccw        = (float*)(ws + 20447232);         // 1024x64 f32     = 262,144
  unsigned char* wq8  = (unsigned char*)(ws + 20709376); // packed fp8      = 12,582,912
  unsigned char* aq8  = (unsigned char*)(ws + 33292288); // packed fp8      = 1,572,864
  unsigned char* qf8  = (unsigned char*)(ws + 34865152); // packed fp8      = 8,388,608
  float* qsc          = (float*)(ws + 43253760);         // 65536 f32       = 262,144
  unsigned char* kf8  = (unsigned char*)(ws + 43515904); // packed fp8      = 131,072
  float* ksc          = (float*)(ws + 43646976);         // 1024 f32        = 4,096

  prep_transpose<<<3872, 256, 0, stream>>>(wq_b, wk, wproj, q_lora, wq8, aq8, BT2);

  // merged: k/w GEMM first (512 short split-K blocks), then q GEMM (MX, LDS)
  gemm_merged<<<1536, 256, 0, stream>>>(aq8, wq8, cs, pos, (u32*)qf8, qsc,
                                        hidden, BT2, kpart);
  k_epilogue<<<128, 256, 0, stream>>>(kpart, knw, knb, cs, pos, (u32*)kf8, ksc, kaccw);

  // logits + causal mask + idx output, MX-scaled
  scores_kernel<<<2048, 256, 0, stream>>>(qf8, kf8, qsc, ksc, kaccw, pos, out);

  (void)in_sizes; (void)n_in; (void)out_size; (void)ws_size;
}